// Round 1
// baseline (94.240 us; speedup 1.0000x reference)
//
#include <hip/hip_runtime.h>
#include <hip/hip_bf16.h>

#define B_DIM 512
#define D_DIM 256
#define C_DIM 100000
#define LAMB 1000.0f

using bf16x8 = __attribute__((ext_vector_type(8))) short;
using f32x4  = __attribute__((ext_vector_type(4))) float;

__device__ __forceinline__ short f2bf(float f) {
  unsigned u = __builtin_bit_cast(unsigned, f);
  u += 0x7FFFu + ((u >> 16) & 1u);      // round-to-nearest-even
  return (short)(u >> 16);
}

// Kernel 1: xlen per row + bf16 x, pre-swizzled (byte ^= (row&7)<<4) so the
// GEMM's linear LDS staging + swizzled ds_read_b128 is bank-conflict-minimal.
__global__ __launch_bounds__(256) void prep_x(const float* __restrict__ x,
                                              unsigned short* __restrict__ x_swz,
                                              float* __restrict__ xlen) {
  int wv = threadIdx.x >> 6, lane = threadIdx.x & 63;
  int row = blockIdx.x * 4 + wv;
  float4 v = *(const float4*)(x + row * D_DIM + lane * 4);
  float ss = v.x * v.x + v.y * v.y + v.z * v.z + v.w * v.w;
#pragma unroll
  for (int m = 1; m < 64; m <<= 1) ss += __shfl_xor(ss, m);
  if (lane == 0) xlen[row] = sqrtf(ss);
  ushort4 u;
  u.x = (unsigned short)f2bf(v.x);
  u.y = (unsigned short)f2bf(v.y);
  u.z = (unsigned short)f2bf(v.z);
  u.w = (unsigned short)f2bf(v.w);
  int byteoff = row * 512 + ((lane * 8) ^ ((row & 7) << 4));
  *(ushort4*)((char*)x_swz + byteoff) = u;
}

// Kernel 2: GEMM. Grid over N only (BM = 512 -> weight read exactly once).
// Block = 4 waves x 32 cols = 128 cols. Wave keeps its 32 weight rows as bf16
// B-fragments in registers (computing inv_wlen from fp32 on the way), then
// streams x through LDS in 8 chunks of 64 rows, MFMA 16x16x32 bf16.
__global__ __launch_bounds__(256) void gemm_bf16(
    const float* __restrict__ W, const unsigned short* __restrict__ x_swz,
    const float* __restrict__ xlen, float* __restrict__ out) {
  __shared__ unsigned short xs[64 * 256];   // 32 KB chunk (swizzled layout)
  __shared__ float xlen_s[B_DIM];

  const int tid = threadIdx.x;
  const int lane = tid & 63, wv = tid >> 6;
  const int l15 = lane & 15, g = lane >> 4;
  const int bn0 = blockIdx.x * 128 + wv * 32;

  for (int i = tid; i < B_DIM; i += 256) xlen_s[i] = xlen[i];

  // ---- Phase 1: weight rows -> registers (bf16) + inv_wlen (fp32) ----
  // B-frag for mfma_f32_16x16x32_bf16: lane holds B[k][col], col = lane&15,
  // k = (lane>>4)*8 + j  (same k-permutation used for the A-frag below).
  bf16x8 fb[2][8];
  float invwl[2];
#pragma unroll
  for (int ns = 0; ns < 2; ++ns) {
    int col = bn0 + ns * 16 + l15;
    if (col >= C_DIM) col = C_DIM - 1;        // clamp; stores are guarded
    const float* wr = W + (size_t)col * D_DIM + g * 8;
    float ss = 0.f;
#pragma unroll
    for (int kg = 0; kg < 8; ++kg) {
      float4 a = *(const float4*)(wr + kg * 32);
      float4 b = *(const float4*)(wr + kg * 32 + 4);
      ss += a.x * a.x + a.y * a.y + a.z * a.z + a.w * a.w
          + b.x * b.x + b.y * b.y + b.z * b.z + b.w * b.w;
      bf16x8 f;
      f[0] = f2bf(a.x); f[1] = f2bf(a.y); f[2] = f2bf(a.z); f[3] = f2bf(a.w);
      f[4] = f2bf(b.x); f[5] = f2bf(b.y); f[6] = f2bf(b.z); f[7] = f2bf(b.w);
      fb[ns][kg] = f;
    }
    // reduce sum-of-squares across the 4 lane-groups (same l15)
    ss += __shfl_xor(ss, 16);
    ss += __shfl_xor(ss, 32);
    invwl[ns] = 1.0f / sqrtf(ss);
  }

  // ---- Phase 2: stream x through LDS, 8 chunks of 64 rows ----
  for (int chunk = 0; chunk < 8; ++chunk) {
    __syncthreads();  // previous chunk fully consumed
    {
      const int4* src = (const int4*)x_swz + chunk * 2048;
      int4* dst = (int4*)xs;
#pragma unroll
      for (int i = 0; i < 8; ++i) dst[i * 256 + tid] = src[i * 256 + tid];
    }
    __syncthreads();

    f32x4 acc[4][2] = {};
#pragma unroll
    for (int kg = 0; kg < 8; ++kg) {
      bf16x8 fa[4];
#pragma unroll
      for (int m = 0; m < 4; ++m) {
        int row = m * 16 + l15;                       // A row = lane&15
        int off = row * 512 + ((kg * 64 + g * 16) ^ ((row & 7) << 4));
        fa[m] = *(const bf16x8*)((const char*)xs + off);
      }
#pragma unroll
      for (int m = 0; m < 4; ++m)
#pragma unroll
        for (int ns = 0; ns < 2; ++ns)
          acc[m][ns] = __builtin_amdgcn_mfma_f32_16x16x32_bf16(
              fa[m], fb[ns][kg], acc[m][ns], 0, 0, 0);
    }

    // epilogue: feat = clamp(dot * inv_wlen, -xlen, xlen)
#pragma unroll
    for (int m = 0; m < 4; ++m) {
#pragma unroll
      for (int ns = 0; ns < 2; ++ns) {
        int col = bn0 + ns * 16 + l15;
        if (col < C_DIM) {
#pragma unroll
          for (int r = 0; r < 4; ++r) {
            int row = chunk * 64 + m * 16 + g * 4 + r;  // C/D: row=(lane>>4)*4+r
            float xl = xlen_s[row];
            float v = acc[m][ns][r] * invwl[ns];
            v = fminf(fmaxf(v, -xl), xl);
            out[(size_t)row * C_DIM + col] = v;
          }
        }
      }
    }
  }
}

// Kernel 3: exact fp32 recompute of the 512 label positions (margin math).
__global__ __launch_bounds__(256) void fix_labels(const float* __restrict__ x,
                                                  const float* __restrict__ W,
                                                  const int* __restrict__ y,
                                                  float* __restrict__ out) {
  int wv = threadIdx.x >> 6, lane = threadIdx.x & 63;
  int b = blockIdx.x * 4 + wv;
  int c = y[b];
  float4 wvv = *(const float4*)(W + (size_t)c * D_DIM + lane * 4);
  float4 xv  = *(const float4*)(x + b * D_DIM + lane * 4);
  float dt = wvv.x * xv.x + wvv.y * xv.y + wvv.z * xv.z + wvv.w * xv.w;
  float sw = wvv.x * wvv.x + wvv.y * wvv.y + wvv.z * wvv.z + wvv.w * wvv.w;
  float sx = xv.x * xv.x + xv.y * xv.y + xv.z * xv.z + xv.w * xv.w;
#pragma unroll
  for (int m = 1; m < 64; m <<= 1) {
    dt += __shfl_xor(dt, m);
    sw += __shfl_xor(sw, m);
    sx += __shfl_xor(sx, m);
  }
  if (lane == 0) {
    float xl = sqrtf(sx), wl = sqrtf(sw);
    float cth = dt / (xl * wl);
    cth = fminf(fmaxf(cth, -1.f), 1.f);
    float c2 = cth * cth;
    float cm = 8.f * c2 * c2 - 8.f * c2 + 1.f;          // cos(4t) Chebyshev
    float k = floorf(4.0f * acosf(cth) / 3.14159265358979323846f);
    float sgn = (((int)k) & 1) ? -1.f : 1.f;
    float phi = sgn * cm - 2.f * k;
    float feat = cth * xl;
    out[(size_t)b * C_DIM + c] = feat + (phi * xl - feat) / (1.f + LAMB);
  }
}

extern "C" void kernel_launch(void* const* d_in, const int* in_sizes, int n_in,
                              void* d_out, int out_size, void* d_ws, size_t ws_size,
                              hipStream_t stream) {
  const float* x = (const float*)d_in[0];
  const float* W = (const float*)d_in[1];
  const int*   y = (const int*)d_in[2];
  float* out = (float*)d_out;

  unsigned short* x_swz = (unsigned short*)d_ws;                 // 256 KB
  float* xlen = (float*)((char*)d_ws + B_DIM * D_DIM * 2);       // 2 KB

  prep_x<<<B_DIM / 4, 256, 0, stream>>>(x, x_swz, xlen);
  gemm_bf16<<<(C_DIM + 127) / 128, 256, 0, stream>>>(W, x_swz, xlen, out);
  fix_labels<<<B_DIM / 4, 256, 0, stream>>>(x, W, y, out);
}